// Round 3
// baseline (307.499 us; speedup 1.0000x reference)
//
#include <hip/hip_runtime.h>
#include <hip/hip_bf16.h>

typedef __bf16 bf16;
typedef __bf16 bf16x4 __attribute__((ext_vector_type(4)));
typedef __bf16 bf16x8 __attribute__((ext_vector_type(8)));
typedef float f32x4 __attribute__((ext_vector_type(4)));
typedef float f32x16 __attribute__((ext_vector_type(16)));
typedef unsigned int uint4v __attribute__((ext_vector_type(4)));

// ---------------------------------------------------------------------------
// async global->LDS, 16B per lane. LDS dest must be wave-uniform base.
// ---------------------------------------------------------------------------
__device__ __forceinline__ void gld_lds16(const void* g, void* l) {
  __builtin_amdgcn_global_load_lds(
      (const __attribute__((address_space(1))) void*)g,
      (__attribute__((address_space(3))) void*)l, 16, 0, 0);
}

__device__ __forceinline__ unsigned pkbf(float a, float b) {
  union { bf16 h[2]; unsigned u; } x;
  x.h[0] = (bf16)a; x.h[1] = (bf16)b;
  return x.u;
}

// ---------------------------------------------------------------------------
// fp32 -> bf16 convert, 4 elems/thread
// ---------------------------------------------------------------------------
__global__ __launch_bounds__(256) void cvt_kernel(const float* __restrict__ src,
                                                  bf16* __restrict__ dst, int n4) {
  int i = blockIdx.x * 256 + threadIdx.x;
  if (i < n4) {
    float4 v = ((const float4*)src)[i];
    bf16x4 o = { (bf16)v.x, (bf16)v.y, (bf16)v.z, (bf16)v.w };
    ((bf16x4*)dst)[i] = o;
  }
}

// ---------------------------------------------------------------------------
// [R][C] fp32  ->  [C][R] bf16
// ---------------------------------------------------------------------------
__global__ __launch_bounds__(256) void transpose_cvt_kernel(const float* __restrict__ src,
                                                            bf16* __restrict__ dst,
                                                            int R, int C) {
  __shared__ float tile[32][33];
  int tx = threadIdx.x & 31, ty = threadIdx.x >> 5;
  int bx = blockIdx.x * 32, by = blockIdx.y * 32;
#pragma unroll
  for (int j = 0; j < 32; j += 8)
    tile[ty + j][tx] = src[(size_t)(by + ty + j) * C + bx + tx];
  __syncthreads();
#pragma unroll
  for (int j = 0; j < 32; j += 8)
    dst[(size_t)(bx + ty + j) * R + by + tx] = (bf16)tile[tx][ty + j];
}

// ---------------------------------------------------------------------------
// bf16 transpose: src [32][2048][64] -> dst [32][64][2048]  (V -> V^T)
// ---------------------------------------------------------------------------
__global__ __launch_bounds__(256) void transpose_v_kernel(const bf16* __restrict__ src,
                                                          bf16* __restrict__ dst) {
  __shared__ bf16 tile[32][34];  // 68B row stride: conflict-free transpose read
  int bh = blockIdx.z;
  int t0 = blockIdx.x * 32;
  int d0 = blockIdx.y * 32;
  int tx = threadIdx.x & 31, ty = threadIdx.x >> 5;  // 32 x 8
  const bf16* s = src + (size_t)bh * 2048 * 64;
  bf16* d = dst + (size_t)bh * 64 * 2048;
#pragma unroll
  for (int j = 0; j < 32; j += 8)
    tile[ty + j][tx] = s[(size_t)(t0 + ty + j) * 64 + d0 + tx];
  __syncthreads();
#pragma unroll
  for (int j = 0; j < 32; j += 8)
    d[(size_t)(d0 + ty + j) * 2048 + t0 + tx] = tile[tx][ty + j];
}

// ---------------------------------------------------------------------------
// m97-structure GEMM: C[M,N] = A[M,K] * BT[N,K]^T
// MODE 1: scatter Q,K,V all row-major [BH][T][64] (coalesced; V^T made later)
// MODE 2: plain fp32 store
// ---------------------------------------------------------------------------
template <int MODE>
__global__ __launch_bounds__(256) void gemm_kernel(
    const bf16* __restrict__ A, const bf16* __restrict__ BT,
    float* __restrict__ Cf, bf16* __restrict__ qb, bf16* __restrict__ kb,
    bf16* __restrict__ vb, int M, int N, int K) {
  __shared__ bf16 As[128 * 32];
  __shared__ bf16 Bs[128 * 32];
  const int t = threadIdx.x;
  const int w = t >> 6, l = t & 63;
  const int bm = blockIdx.y * 128, bn = blockIdx.x * 128;
  const int wr = (w >> 1) * 64, wc = (w & 1) * 64;
  const int lr = l & 15, lh = l >> 4;
  f32x4 acc[4][4] = {};

  const bf16* Ab = A + (size_t)bm * K;
  const bf16* Bb = BT + (size_t)bn * K;
  const int srow = t >> 2;
  const int scol = (t & 3) * 8;
  char* AsB = (char*)As;
  char* BsB = (char*)Bs;
  const int ldsw = w * 1024;

  for (int k0 = 0; k0 < K; k0 += 32) {
    __syncthreads();
    gld_lds16(Ab + (size_t)srow * K + k0 + scol, AsB + ldsw);
    gld_lds16(Ab + (size_t)(srow + 64) * K + k0 + scol, AsB + 4096 + ldsw);
    gld_lds16(Bb + (size_t)srow * K + k0 + scol, BsB + ldsw);
    gld_lds16(Bb + (size_t)(srow + 64) * K + k0 + scol, BsB + 4096 + ldsw);
    __syncthreads();
    bf16x8 af[4], bfr[4];
#pragma unroll
    for (int m = 0; m < 4; ++m)
      af[m] = *(const bf16x8*)(AsB + (wr + m * 16 + lr) * 64 + lh * 16);
#pragma unroll
    for (int n = 0; n < 4; ++n)
      bfr[n] = *(const bf16x8*)(BsB + (wc + n * 16 + lr) * 64 + lh * 16);
#pragma unroll
    for (int m = 0; m < 4; ++m)
#pragma unroll
      for (int n = 0; n < 4; ++n)
        acc[m][n] = __builtin_amdgcn_mfma_f32_16x16x32_bf16(af[m], bfr[n],
                                                            acc[m][n], 0, 0, 0);
  }

  const int r0 = bm + wr + (lh << 2);
  const int c0 = bn + wc + lr;
#pragma unroll
  for (int m = 0; m < 4; ++m) {
#pragma unroll
    for (int n = 0; n < 4; ++n) {
#pragma unroll
      for (int r = 0; r < 4; ++r) {
        float v = acc[m][n][r];
        int row = r0 + m * 16 + r;
        int col = c0 + n * 16;
        if (MODE == 2) {
          Cf[(size_t)row * N + col] = v;
        } else {
          int bb = row >> 11, tt = row & 2047;
          if (col < 1024) {
            int h = col >> 6, d = col & 63;
            qb[(((size_t)(bb * 16 + h)) * 2048 + tt) * 64 + d] = (bf16)v;
          } else if (col < 2048) {
            int c = col - 1024, h = c >> 6, d = c & 63;
            kb[(((size_t)(bb * 16 + h)) * 2048 + tt) * 64 + d] = (bf16)v;
          } else {
            int c = col - 2048, h = c >> 6, d = c & 63;
            vb[(((size_t)(bb * 16 + h)) * 2048 + tt) * 64 + d] = (bf16)v;
          }
        }
      }
    }
  }
}

// ---------------------------------------------------------------------------
// Causal flash attention, swapped-QK^T 32x32x16, WORK-BALANCED.
// grid (16,32) = 512 blocks, 4 waves. Wave handles TWO 32-row q-chunks:
// jj (jj+1 kv-steps) and 63-jj (64-jj steps) -> exactly 65 steps per wave.
// Waves fully independent (wave-private LDS epilogue slice, no barrier).
// S^T = mfma(K,Q): lane owns full q-row. O^T = mfma(V^T,P^T): softmax
// state lane-local. Register double-buffer K/V prefetch. Defer-max.
// ---------------------------------------------------------------------------
__global__ __launch_bounds__(256) void attn_kernel(const bf16* __restrict__ qb,
                                                   const bf16* __restrict__ kb,
                                                   const bf16* __restrict__ vt,
                                                   bf16* __restrict__ ao) {
  __shared__ bf16 plds[4][32][72];
  int wid = blockIdx.y * 16 + blockIdx.x;
  int swz = (wid & 7) * 64 + (wid >> 3);  // 4 heads/XCD -> K/V L2-resident
  const int bh = swz >> 4;
  const int grp = swz & 15;
  const int w = threadIdx.x >> 6, l = threadIdx.x & 63;
  const int jj = grp * 4 + w;             // 0..63, unique per (bh, wave)
  const int lq = l & 31, hi = l >> 5;
  const bf16* Qh = qb + (size_t)bh * 2048 * 64;
  const bf16* Kh = kb + (size_t)bh * 2048 * 64;
  const bf16* Vh = vt + (size_t)bh * 64 * 2048;
  const int bb = bh >> 4, h = bh & 15;
  const float sc2 = 0.125f * 1.4426950408889634f;  // scale * log2(e)

#pragma unroll 1
  for (int phase = 0; phase < 2; ++phase) {
    const int qw = (phase ? (63 - jj) : jj) * 32;
    const int lastkt = qw >> 5;

    bf16x8 qf[4];
#pragma unroll
    for (int c = 0; c < 4; ++c)
      qf[c] = *(const bf16x8*)(Qh + (size_t)(qw + lq) * 64 + c * 16 + hi * 8);

    f32x16 Ot0, Ot1;
#pragma unroll
    for (int r = 0; r < 16; ++r) { Ot0[r] = 0.f; Ot1[r] = 0.f; }
    float mrun = -1e30f, srun = 0.f;

    bf16x8 kA[4], vA[4], kB[4], vB[4];
#pragma unroll
    for (int c = 0; c < 4; ++c)
      kA[c] = *(const bf16x8*)(Kh + (size_t)lq * 64 + c * 16 + hi * 8);
#pragma unroll
    for (int df = 0; df < 2; ++df)
#pragma unroll
      for (int c = 0; c < 2; ++c)
        vA[df * 2 + c] = *(const bf16x8*)(Vh + (size_t)(df * 32 + lq) * 2048 + c * 16 + hi * 8);

    auto step = [&](bf16x8 (&KC)[4], bf16x8 (&VC)[4],
                    bf16x8 (&KN)[4], bf16x8 (&VN)[4], int kt) {
      const int kv0 = kt << 5;
      const int nkv0 = (kt < lastkt) ? kv0 + 32 : kv0;
#pragma unroll
      for (int c = 0; c < 4; ++c)
        KN[c] = *(const bf16x8*)(Kh + (size_t)(nkv0 + lq) * 64 + c * 16 + hi * 8);
#pragma unroll
      for (int df = 0; df < 2; ++df)
#pragma unroll
        for (int c = 0; c < 2; ++c)
          VN[df * 2 + c] = *(const bf16x8*)(Vh + (size_t)(df * 32 + lq) * 2048 + nkv0 + c * 16 + hi * 8);

      f32x16 S;
#pragma unroll
      for (int r = 0; r < 16; ++r) S[r] = 0.f;
#pragma unroll
      for (int c = 0; c < 4; ++c)
        S = __builtin_amdgcn_mfma_f32_32x32x16_bf16(KC[c], qf[c], S, 0, 0, 0);

      if (kt == lastkt) {  // causal diagonal tile (kv0 == qw)
#pragma unroll
        for (int r = 0; r < 16; ++r) {
          int kvl = (r & 3) + 8 * (r >> 2) + 4 * hi;
          if (kvl > lq) S[r] = -1e30f;
        }
      }

      float mx[8];
#pragma unroll
      for (int i = 0; i < 8; ++i) mx[i] = fmaxf(S[2 * i], S[2 * i + 1]);
#pragma unroll
      for (int i = 0; i < 4; ++i) mx[i] = fmaxf(mx[i], mx[i + 4]);
      mx[0] = fmaxf(mx[0], mx[2]); mx[1] = fmaxf(mx[1], mx[3]);
      float smax = fmaxf(mx[0], mx[1]);
      float vmax = fmaxf(smax, __shfl_xor(smax, 32, 64));

      float mn = mrun;
      if (!__all(vmax <= mrun + 64.0f)) {  // 64 raw = 8 nat-exp units
        mn = fmaxf(mrun, vmax);
        float al = exp2f((mrun - mn) * sc2);
        srun *= al;
#pragma unroll
        for (int r = 0; r < 16; ++r) { Ot0[r] *= al; Ot1[r] *= al; }
        mrun = mn;
      }

      const float nb = -mn * sc2;
      float ps = 0.f;
      unsigned u_[8];
#pragma unroll
      for (int i = 0; i < 8; ++i) {
        float pa = exp2f(fmaf(S[2 * i], sc2, nb));
        float pb = exp2f(fmaf(S[2 * i + 1], sc2, nb));
        ps += pa + pb;
        u_[i] = pkbf(pa, pb);
      }
      ps += __shfl_xor(ps, 32, 64);
      srun += ps;

      unsigned s_[8];
#pragma unroll
      for (int i = 0; i < 8; ++i) s_[i] = __shfl_xor(u_[i], 32, 64);

      uint4v f0 = hi ? (uint4v){s_[2], s_[3], u_[2], u_[3]}
                     : (uint4v){u_[0], u_[1], s_[0], s_[1]};
      uint4v f1 = hi ? (uint4v){s_[6], s_[7], u_[6], u_[7]}
                     : (uint4v){u_[4], u_[5], s_[4], s_[5]};
      bf16x8 pf0 = __builtin_bit_cast(bf16x8, f0);
      bf16x8 pf1 = __builtin_bit_cast(bf16x8, f1);

      Ot0 = __builtin_amdgcn_mfma_f32_32x32x16_bf16(VC[0], pf0, Ot0, 0, 0, 0);
      Ot0 = __builtin_amdgcn_mfma_f32_32x32x16_bf16(VC[1], pf1, Ot0, 0, 0, 0);
      Ot1 = __builtin_amdgcn_mfma_f32_32x32x16_bf16(VC[2], pf0, Ot1, 0, 0, 0);
      Ot1 = __builtin_amdgcn_mfma_f32_32x32x16_bf16(VC[3], pf1, Ot1, 0, 0, 0);
    };

    for (int kt = 0; kt <= lastkt; ++kt) {
      if ((kt & 1) == 0) step(kA, vA, kB, vB, kt);
      else               step(kB, vB, kA, vA, kt);
    }

    // epilogue: O^T -> wave-private LDS transpose -> coalesced 16B stores
    float inv = 1.0f / srun;
#pragma unroll
    for (int r = 0; r < 16; r += 2) {
      int d0 = (r & 3) + 8 * (r >> 2) + 4 * hi;
      *(unsigned*)&plds[w][lq][d0]      = pkbf(Ot0[r] * inv, Ot0[r + 1] * inv);
      *(unsigned*)&plds[w][lq][32 + d0] = pkbf(Ot1[r] * inv, Ot1[r + 1] * inv);
    }
    __builtin_amdgcn_s_waitcnt(0);  // lgkm drain: wave-private LDS RAW

    const int q = l >> 1, dh = (l & 1) * 32;
    size_t orow = ((size_t)(bb * 2048 + qw + q)) * 1024 + h * 64 + dh;
#pragma unroll
    for (int c = 0; c < 4; ++c) {
      bf16x8 vv = *(const bf16x8*)&plds[w][q][dh + c * 8];
      *(bf16x8*)(ao + orow + c * 8) = vv;
    }
  }
}

// ---------------------------------------------------------------------------
// launch
// ---------------------------------------------------------------------------
extern "C" void kernel_launch(void* const* d_in, const int* in_sizes, int n_in,
                              void* d_out, int out_size, void* d_ws, size_t ws_size,
                              hipStream_t stream) {
  const float* x = (const float*)d_in[0];
  // d_in[1] = causal mask — implemented analytically
  const float* Wqkv = (const float*)d_in[2];
  const float* Wout = (const float*)d_in[3];
  float* out = (float*)d_out;

  char* ws = (char*)d_ws;
  bf16* xb  = (bf16*)(ws);                        // 8 MB
  bf16* wqT = (bf16*)(ws + (size_t)(8 << 20));    // 6 MB
  bf16* woT = (bf16*)(ws + (size_t)(14 << 20));   // 2 MB
  bf16* qb  = (bf16*)(ws + (size_t)(16 << 20));   // 8 MB
  bf16* kb  = (bf16*)(ws + (size_t)(24 << 20));   // 8 MB
  bf16* vt  = (bf16*)(ws + (size_t)(32 << 20));   // 8 MB  V^T
  bf16* ao  = (bf16*)(ws + (size_t)(40 << 20));   // 8 MB
  bf16* vb  = (bf16*)(ws + (size_t)(48 << 20));   // 8 MB  V row-major

  cvt_kernel<<<dim3(4096), dim3(256), 0, stream>>>(x, xb, 1048576);
  transpose_cvt_kernel<<<dim3(96, 32), dim3(256), 0, stream>>>(Wqkv, wqT, 1024, 3072);
  transpose_cvt_kernel<<<dim3(32, 32), dim3(256), 0, stream>>>(Wout, woT, 1024, 1024);
  gemm_kernel<1><<<dim3(24, 32), dim3(256), 0, stream>>>(xb, wqT, nullptr, qb, kb, vb,
                                                         4096, 3072, 1024);
  transpose_v_kernel<<<dim3(64, 2, 32), dim3(256), 0, stream>>>(vb, vt);
  attn_kernel<<<dim3(16, 32), dim3(256), 0, stream>>>(qb, kb, vt, ao);
  gemm_kernel<2><<<dim3(8, 32), dim3(256), 0, stream>>>(ao, woT, out, nullptr, nullptr,
                                                        nullptr, 4096, 1024, 1024);
}

// Round 5
// 228.953 us; speedup vs baseline: 1.3431x; 1.3431x over previous
//
#include <hip/hip_runtime.h>
#include <hip/hip_bf16.h>

typedef __bf16 bf16;
typedef __bf16 bf16x4 __attribute__((ext_vector_type(4)));
typedef __bf16 bf16x8 __attribute__((ext_vector_type(8)));
typedef float f32x4 __attribute__((ext_vector_type(4)));
typedef float f32x16 __attribute__((ext_vector_type(16)));
typedef unsigned int uint4v __attribute__((ext_vector_type(4)));

// ---------------------------------------------------------------------------
// async global->LDS, 16B per lane. LDS dest must be wave-uniform base.
// ---------------------------------------------------------------------------
__device__ __forceinline__ void gld_lds16(const void* g, void* l) {
  __builtin_amdgcn_global_load_lds(
      (const __attribute__((address_space(1))) void*)g,
      (__attribute__((address_space(3))) void*)l, 16, 0, 0);
}

__device__ __forceinline__ unsigned pkbf(float a, float b) {
  union { bf16 h[2]; unsigned u; } x;
  x.h[0] = (bf16)a; x.h[1] = (bf16)b;
  return x.u;
}

// v_permlane32_swap_b32 with forced-distinct registers.
// Doc model: a' = {a.lanes0-31 | b.lanes0-31}, b' = {a.lanes32-63 | b.lanes32-63}.
// The empty asm makes a,b opaque-distinct so regalloc can NEVER coalesce them
// onto one physreg (the round-4 bug when a==b on entry).
__device__ __forceinline__ void plswap2(unsigned& a, unsigned& b) {
  asm volatile("" : "+v"(a), "+v"(b));
  asm("v_permlane32_swap_b32 %0, %1" : "+v"(a), "+v"(b));
}

__device__ __forceinline__ float asf(unsigned u) { return __builtin_bit_cast(float, u); }

// cross-half max/sum — correct under EITHER output convention of the swap
__device__ __forceinline__ float plmax(float x) {
  unsigned a = __builtin_bit_cast(unsigned, x), b = a;
  plswap2(a, b);
  return fmaxf(asf(a), asf(b));
}
__device__ __forceinline__ float plsum(float x) {
  unsigned a = __builtin_bit_cast(unsigned, x), b = a;
  plswap2(a, b);
  return asf(a) + asf(b);
}

// ---------------------------------------------------------------------------
// fp32 -> bf16 convert, 4 elems/thread
// ---------------------------------------------------------------------------
__global__ __launch_bounds__(256) void cvt_kernel(const float* __restrict__ src,
                                                  bf16* __restrict__ dst, int n4) {
  int i = blockIdx.x * 256 + threadIdx.x;
  if (i < n4) {
    float4 v = ((const float4*)src)[i];
    bf16x4 o = { (bf16)v.x, (bf16)v.y, (bf16)v.z, (bf16)v.w };
    ((bf16x4*)dst)[i] = o;
  }
}

// ---------------------------------------------------------------------------
// [R][C] fp32  ->  [C][R] bf16
// ---------------------------------------------------------------------------
__global__ __launch_bounds__(256) void transpose_cvt_kernel(const float* __restrict__ src,
                                                            bf16* __restrict__ dst,
                                                            int R, int C) {
  __shared__ float tile[32][33];
  int tx = threadIdx.x & 31, ty = threadIdx.x >> 5;
  int bx = blockIdx.x * 32, by = blockIdx.y * 32;
#pragma unroll
  for (int j = 0; j < 32; j += 8)
    tile[ty + j][tx] = src[(size_t)(by + ty + j) * C + bx + tx];
  __syncthreads();
#pragma unroll
  for (int j = 0; j < 32; j += 8)
    dst[(size_t)(bx + ty + j) * R + by + tx] = (bf16)tile[tx][ty + j];
}

// ---------------------------------------------------------------------------
// bf16 transpose: src [32][2048][64] -> dst [32][64][2048]  (V -> V^T)
// ---------------------------------------------------------------------------
__global__ __launch_bounds__(256) void transpose_v_kernel(const bf16* __restrict__ src,
                                                          bf16* __restrict__ dst) {
  __shared__ bf16 tile[32][34];
  int bh = blockIdx.z;
  int t0 = blockIdx.x * 32;
  int d0 = blockIdx.y * 32;
  int tx = threadIdx.x & 31, ty = threadIdx.x >> 5;
  const bf16* s = src + (size_t)bh * 2048 * 64;
  bf16* d = dst + (size_t)bh * 64 * 2048;
#pragma unroll
  for (int j = 0; j < 32; j += 8)
    tile[ty + j][tx] = s[(size_t)(t0 + ty + j) * 64 + d0 + tx];
  __syncthreads();
#pragma unroll
  for (int j = 0; j < 32; j += 8)
    d[(size_t)(d0 + ty + j) * 2048 + t0 + tx] = tile[tx][ty + j];
}

// ---------------------------------------------------------------------------
// m97-structure GEMM: C[M,N] = A[M,K] * BT[N,K]^T
// MODE 1: scatter Q,K,V row-major [BH][T][64]; MODE 2: fp32 store
// ---------------------------------------------------------------------------
template <int MODE>
__global__ __launch_bounds__(256) void gemm_kernel(
    const bf16* __restrict__ A, const bf16* __restrict__ BT,
    float* __restrict__ Cf, bf16* __restrict__ qb, bf16* __restrict__ kb,
    bf16* __restrict__ vb, int M, int N, int K) {
  __shared__ bf16 As[128 * 32];
  __shared__ bf16 Bs[128 * 32];
  const int t = threadIdx.x;
  const int w = t >> 6, l = t & 63;
  const int bm = blockIdx.y * 128, bn = blockIdx.x * 128;
  const int wr = (w >> 1) * 64, wc = (w & 1) * 64;
  const int lr = l & 15, lh = l >> 4;
  f32x4 acc[4][4] = {};

  const bf16* Ab = A + (size_t)bm * K;
  const bf16* Bb = BT + (size_t)bn * K;
  const int srow = t >> 2;
  const int scol = (t & 3) * 8;
  char* AsB = (char*)As;
  char* BsB = (char*)Bs;
  const int ldsw = w * 1024;

  for (int k0 = 0; k0 < K; k0 += 32) {
    __syncthreads();
    gld_lds16(Ab + (size_t)srow * K + k0 + scol, AsB + ldsw);
    gld_lds16(Ab + (size_t)(srow + 64) * K + k0 + scol, AsB + 4096 + ldsw);
    gld_lds16(Bb + (size_t)srow * K + k0 + scol, BsB + ldsw);
    gld_lds16(Bb + (size_t)(srow + 64) * K + k0 + scol, BsB + 4096 + ldsw);
    __syncthreads();
    bf16x8 af[4], bfr[4];
#pragma unroll
    for (int m = 0; m < 4; ++m)
      af[m] = *(const bf16x8*)(AsB + (wr + m * 16 + lr) * 64 + lh * 16);
#pragma unroll
    for (int n = 0; n < 4; ++n)
      bfr[n] = *(const bf16x8*)(BsB + (wc + n * 16 + lr) * 64 + lh * 16);
#pragma unroll
    for (int m = 0; m < 4; ++m)
#pragma unroll
      for (int n = 0; n < 4; ++n)
        acc[m][n] = __builtin_amdgcn_mfma_f32_16x16x32_bf16(af[m], bfr[n],
                                                            acc[m][n], 0, 0, 0);
  }

  const int r0 = bm + wr + (lh << 2);
  const int c0 = bn + wc + lr;
#pragma unroll
  for (int m = 0; m < 4; ++m) {
#pragma unroll
    for (int n = 0; n < 4; ++n) {
#pragma unroll
      for (int r = 0; r < 4; ++r) {
        float v = acc[m][n][r];
        int row = r0 + m * 16 + r;
        int col = c0 + n * 16;
        if (MODE == 2) {
          Cf[(size_t)row * N + col] = v;
        } else {
          int bb = row >> 11, tt = row & 2047;
          if (col < 1024) {
            int h = col >> 6, d = col & 63;
            qb[(((size_t)(bb * 16 + h)) * 2048 + tt) * 64 + d] = (bf16)v;
          } else if (col < 2048) {
            int c = col - 1024, h = c >> 6, d = c & 63;
            kb[(((size_t)(bb * 16 + h)) * 2048 + tt) * 64 + d] = (bf16)v;
          } else {
            int c = col - 2048, h = c >> 6, d = c & 63;
            vb[(((size_t)(bb * 16 + h)) * 2048 + tt) * 64 + d] = (bf16)v;
          }
        }
      }
    }
  }
}

// ---------------------------------------------------------------------------
// Causal flash attention, swapped-QK^T 32x32x16, balanced + de-duplicated.
// grid (8,32) = 256 blocks, 4 waves. jj = grp*4+w in 0..31; wave handles
// chunks {jj, 63-jj} -> exactly 65 kv-steps per wave, each chunk ONCE.
// Cross-lane via v_permlane32_swap, made convention-independent:
// reductions use max/sum of both swap outputs; P-fragment word order is
// selected by a runtime-probed wave-uniform 'flipped' flag.
// ---------------------------------------------------------------------------
__global__ __launch_bounds__(256) void attn_kernel(const bf16* __restrict__ qb,
                                                   const bf16* __restrict__ kb,
                                                   const bf16* __restrict__ vt,
                                                   bf16* __restrict__ ao) {
  __shared__ bf16 plds[4][32][72];
  int wid = blockIdx.y * 8 + blockIdx.x;
  int swz = (wid & 7) * 32 + (wid >> 3);  // XCD x -> heads 4x..4x+3 (L2-resident)
  const int bh = swz >> 3;
  const int grp = swz & 7;
  const int w = threadIdx.x >> 6, l = threadIdx.x & 63;
  const int jj = grp * 4 + w;             // 0..31, unique per (bh, wave)
  const int lq = l & 31, hi = l >> 5;
  const bf16* Qh = qb + (size_t)bh * 2048 * 64;
  const bf16* Kh = kb + (size_t)bh * 2048 * 64;
  const bf16* Vh = vt + (size_t)bh * 64 * 2048;
  const int bb = bh >> 4, h = bh & 15;
  const float sc2 = 0.125f * 1.4426950408889634f;  // scale * log2(e)

  // probe the swap's output convention once (wave-uniform result)
  unsigned ta = (unsigned)l, tb = (unsigned)l;
  plswap2(ta, tb);
  const bool flipped = (ta != (unsigned)(l & 31));  // doc model: ta holds low half

#pragma unroll 1
  for (int phase = 0; phase < 2; ++phase) {
    const int qw = (phase ? (63 - jj) : jj) * 32;
    const int lastkt = qw >> 5;

    bf16x8 qf[4];
#pragma unroll
    for (int c = 0; c < 4; ++c)
      qf[c] = *(const bf16x8*)(Qh + (size_t)(qw + lq) * 64 + c * 16 + hi * 8);

    f32x16 Ot0, Ot1;
#pragma unroll
    for (int r = 0; r < 16; ++r) { Ot0[r] = 0.f; Ot1[r] = 0.f; }
    float mrun = -1e30f, srun = 0.f;

    bf16x8 kA[4], vA[4], kB[4], vB[4];
#pragma unroll
    for (int c = 0; c < 4; ++c)
      kA[c] = *(const bf16x8*)(Kh + (size_t)lq * 64 + c * 16 + hi * 8);
#pragma unroll
    for (int df = 0; df < 2; ++df)
#pragma unroll
      for (int c = 0; c < 2; ++c)
        vA[df * 2 + c] = *(const bf16x8*)(Vh + (size_t)(df * 32 + lq) * 2048 + c * 16 + hi * 8);

    auto step = [&](bf16x8 (&KC)[4], bf16x8 (&VC)[4],
                    bf16x8 (&KN)[4], bf16x8 (&VN)[4], int kt) {
      const int kv0 = kt << 5;
      const int nkv0 = (kt < lastkt) ? kv0 + 32 : kv0;
#pragma unroll
      for (int c = 0; c < 4; ++c)
        KN[c] = *(const bf16x8*)(Kh + (size_t)(nkv0 + lq) * 64 + c * 16 + hi * 8);
#pragma unroll
      for (int df = 0; df < 2; ++df)
#pragma unroll
        for (int c = 0; c < 2; ++c)
          VN[df * 2 + c] = *(const bf16x8*)(Vh + (size_t)(df * 32 + lq) * 2048 + nkv0 + c * 16 + hi * 8);

      f32x16 S;
#pragma unroll
      for (int r = 0; r < 16; ++r) S[r] = 0.f;
#pragma unroll
      for (int c = 0; c < 4; ++c)
        S = __builtin_amdgcn_mfma_f32_32x32x16_bf16(KC[c], qf[c], S, 0, 0, 0);

      if (kt == lastkt) {  // causal diagonal tile (kv0 == qw)
#pragma unroll
        for (int r = 0; r < 16; ++r) {
          int kvl = (r & 3) + 8 * (r >> 2) + 4 * hi;
          if (kvl > lq) S[r] = -1e30f;
        }
      }

      float mx[8];
#pragma unroll
      for (int i = 0; i < 8; ++i) mx[i] = fmaxf(S[2 * i], S[2 * i + 1]);
#pragma unroll
      for (int i = 0; i < 4; ++i) mx[i] = fmaxf(mx[i], mx[i + 4]);
      mx[0] = fmaxf(mx[0], mx[2]); mx[1] = fmaxf(mx[1], mx[3]);
      float smax = fmaxf(mx[0], mx[1]);
      float vmax = plmax(smax);  // full-row max, convention-independent

      float mn = mrun;
      if (!__all(vmax <= mrun + 64.0f)) {  // 64 raw = 8 nat-exp units
        mn = fmaxf(mrun, vmax);
        float al = exp2f((mrun - mn) * sc2);
        srun *= al;
#pragma unroll
        for (int r = 0; r < 16; ++r) { Ot0[r] *= al; Ot1[r] *= al; }
        mrun = mn;
      }

      const float nb = -mn * sc2;
      float ps = 0.f;
      unsigned u_[8];
#pragma unroll
      for (int i = 0; i < 8; ++i) {
        float pa = exp2f(fmaf(S[2 * i], sc2, nb));
        float pb = exp2f(fmaf(S[2 * i + 1], sc2, nb));
        ps += pa + pb;
        u_[i] = pkbf(pa, pb);
      }
      srun += plsum(ps);  // full-row sum, convention-independent

      // P^T B-frags via permlane32_swap: one swap fills two output words.
      unsigned a0 = u_[0], b0 = u_[2]; plswap2(a0, b0);
      unsigned a1 = u_[1], b1 = u_[3]; plswap2(a1, b1);
      unsigned a2 = u_[4], b2 = u_[6]; plswap2(a2, b2);
      unsigned a3 = u_[5], b3 = u_[7]; plswap2(a3, b3);
      // doc model: a* holds {lo|lo-partner} -> words 0,1; b* -> words 2,3.
      // If HW convention is reversed, 'flipped' swaps the roles.
      unsigned w00 = flipped ? b0 : a0, w02 = flipped ? a0 : b0;
      unsigned w01 = flipped ? b1 : a1, w03 = flipped ? a1 : b1;
      unsigned w10 = flipped ? b2 : a2, w12 = flipped ? a2 : b2;
      unsigned w11 = flipped ? b3 : a3, w13 = flipped ? a3 : b3;
      uint4v f0 = {w00, w01, w02, w03};
      uint4v f1 = {w10, w11, w12, w13};
      bf16x8 pf0 = __builtin_bit_cast(bf16x8, f0);
      bf16x8 pf1 = __builtin_bit_cast(bf16x8, f1);

      Ot0 = __builtin_amdgcn_mfma_f32_32x32x16_bf16(VC[0], pf0, Ot0, 0, 0, 0);
      Ot0 = __builtin_amdgcn_mfma_f32_32x32x16_bf16(VC[1], pf1, Ot0, 0, 0, 0);
      Ot1 = __builtin_amdgcn_mfma_f32_32x32x16_bf16(VC[2], pf0, Ot1, 0, 0, 0);
      Ot1 = __builtin_amdgcn_mfma_f32_32x32x16_bf16(VC[3], pf1, Ot1, 0, 0, 0);
    };

    for (int kt = 0; kt <= lastkt; ++kt) {
      if ((kt & 1) == 0) step(kA, vA, kB, vB, kt);
      else               step(kB, vB, kA, vA, kt);
    }

    // epilogue: O^T -> wave-private LDS transpose -> coalesced 16B stores
    float inv = 1.0f / srun;
#pragma unroll
    for (int r = 0; r < 16; r += 2) {
      int d0 = (r & 3) + 8 * (r >> 2) + 4 * hi;
      *(unsigned*)&plds[w][lq][d0]      = pkbf(Ot0[r] * inv, Ot0[r + 1] * inv);
      *(unsigned*)&plds[w][lq][32 + d0] = pkbf(Ot1[r] * inv, Ot1[r + 1] * inv);
    }
    __builtin_amdgcn_s_waitcnt(0);  // wave-private LDS RAW drain

    const int q = l >> 1, dh = (l & 1) * 32;
    size_t orow = ((size_t)(bb * 2048 + qw + q)) * 1024 + h * 64 + dh;
#pragma unroll
    for (int c = 0; c < 4; ++c) {
      bf16x8 vv = *(const bf16x8*)&plds[w][q][dh + c * 8];
      *(bf16x8*)(ao + orow + c * 8) = vv;
    }
  }
}

// ---------------------------------------------------------------------------
// launch
// ---------------------------------------------------------------------------
extern "C" void kernel_launch(void* const* d_in, const int* in_sizes, int n_in,
                              void* d_out, int out_size, void* d_ws, size_t ws_size,
                              hipStream_t stream) {
  const float* x = (const float*)d_in[0];
  // d_in[1] = causal mask — implemented analytically
  const float* Wqkv = (const float*)d_in[2];
  const float* Wout = (const float*)d_in[3];
  float* out = (float*)d_out;

  char* ws = (char*)d_ws;
  bf16* xb  = (bf16*)(ws);                        // 8 MB
  bf16* wqT = (bf16*)(ws + (size_t)(8 << 20));    // 6 MB
  bf16* woT = (bf16*)(ws + (size_t)(14 << 20));   // 2 MB
  bf16* qb  = (bf16*)(ws + (size_t)(16 << 20));   // 8 MB
  bf16* kb  = (bf16*)(ws + (size_t)(24 << 20));   // 8 MB
  bf16* vt  = (bf16*)(ws + (size_t)(32 << 20));   // 8 MB  V^T
  bf16* ao  = (bf16*)(ws + (size_t)(40 << 20));   // 8 MB
  bf16* vb  = (bf16*)(ws + (size_t)(48 << 20));   // 8 MB  V row-major

  cvt_kernel<<<dim3(4096), dim3(256), 0, stream>>>(x, xb, 1048576);
  transpose_cvt_kernel<<<dim3(96, 32), dim3(256), 0, stream>>>(Wqkv, wqT, 1024, 3072);
  transpose_cvt_kernel<<<dim3(32, 32), dim3(256), 0, stream>>>(Wout, woT, 1024, 1024);
  gemm_kernel<1><<<dim3(24, 32), dim3(256), 0, stream>>>(xb, wqT, nullptr, qb, kb, vb,
                                                         4096, 3072, 1024);
  transpose_v_kernel<<<dim3(64, 2, 32), dim3(256), 0, stream>>>(vb, vt);
  attn_kernel<<<dim3(8, 32), dim3(256), 0, stream>>>(qb, kb, vt, ao);
  gemm_kernel<2><<<dim3(8, 32), dim3(256), 0, stream>>>(ao, woT, out, nullptr, nullptr,
                                                        nullptr, 4096, 1024, 1024);
}

// Round 6
// 227.390 us; speedup vs baseline: 1.3523x; 1.0069x over previous
//
#include <hip/hip_runtime.h>
#include <hip/hip_bf16.h>

typedef __bf16 bf16;
typedef __bf16 bf16x4 __attribute__((ext_vector_type(4)));
typedef __bf16 bf16x8 __attribute__((ext_vector_type(8)));
typedef float f32x4 __attribute__((ext_vector_type(4)));
typedef float f32x16 __attribute__((ext_vector_type(16)));
typedef unsigned int uint4v __attribute__((ext_vector_type(4)));

// ---------------------------------------------------------------------------
// async global->LDS, 16B per lane. LDS dest must be wave-uniform base.
// ---------------------------------------------------------------------------
__device__ __forceinline__ void gld_lds16(const void* g, void* l) {
  __builtin_amdgcn_global_load_lds(
      (const __attribute__((address_space(1))) void*)g,
      (__attribute__((address_space(3))) void*)l, 16, 0, 0);
}

__device__ __forceinline__ unsigned pkbf(float a, float b) {
  union { bf16 h[2]; unsigned u; } x;
  x.h[0] = (bf16)a; x.h[1] = (bf16)b;
  return x.u;
}

// v_permlane32_swap_b32 with forced-distinct registers.
// The empty asm makes a,b opaque-distinct so regalloc can NEVER coalesce them
// onto one physreg (the round-4 bug when a==b on entry).
__device__ __forceinline__ void plswap2(unsigned& a, unsigned& b) {
  asm volatile("" : "+v"(a), "+v"(b));
  asm("v_permlane32_swap_b32 %0, %1" : "+v"(a), "+v"(b));
}

__device__ __forceinline__ float asf(unsigned u) { return __builtin_bit_cast(float, u); }

// cross-half max/sum — correct under EITHER output convention of the swap
__device__ __forceinline__ float plmax(float x) {
  unsigned a = __builtin_bit_cast(unsigned, x), b = a;
  plswap2(a, b);
  return fmaxf(asf(a), asf(b));
}
__device__ __forceinline__ float plsum(float x) {
  unsigned a = __builtin_bit_cast(unsigned, x), b = a;
  plswap2(a, b);
  return asf(a) + asf(b);
}

// ---------------------------------------------------------------------------
// fp32 -> bf16 convert, 4 elems/thread
// ---------------------------------------------------------------------------
__global__ __launch_bounds__(256) void cvt_kernel(const float* __restrict__ src,
                                                  bf16* __restrict__ dst, int n4) {
  int i = blockIdx.x * 256 + threadIdx.x;
  if (i < n4) {
    float4 v = ((const float4*)src)[i];
    bf16x4 o = { (bf16)v.x, (bf16)v.y, (bf16)v.z, (bf16)v.w };
    ((bf16x4*)dst)[i] = o;
  }
}

// ---------------------------------------------------------------------------
// [R][C] fp32  ->  [C][R] bf16
// ---------------------------------------------------------------------------
__global__ __launch_bounds__(256) void transpose_cvt_kernel(const float* __restrict__ src,
                                                            bf16* __restrict__ dst,
                                                            int R, int C) {
  __shared__ float tile[32][33];
  int tx = threadIdx.x & 31, ty = threadIdx.x >> 5;
  int bx = blockIdx.x * 32, by = blockIdx.y * 32;
#pragma unroll
  for (int j = 0; j < 32; j += 8)
    tile[ty + j][tx] = src[(size_t)(by + ty + j) * C + bx + tx];
  __syncthreads();
#pragma unroll
  for (int j = 0; j < 32; j += 8)
    dst[(size_t)(bx + ty + j) * R + by + tx] = (bf16)tile[tx][ty + j];
}

// ---------------------------------------------------------------------------
// bf16 transpose: src [32][2048][64] -> dst [32][64][2048]  (V -> V^T)
// ---------------------------------------------------------------------------
__global__ __launch_bounds__(256) void transpose_v_kernel(const bf16* __restrict__ src,
                                                          bf16* __restrict__ dst) {
  __shared__ bf16 tile[32][34];
  int bh = blockIdx.z;
  int t0 = blockIdx.x * 32;
  int d0 = blockIdx.y * 32;
  int tx = threadIdx.x & 31, ty = threadIdx.x >> 5;
  const bf16* s = src + (size_t)bh * 2048 * 64;
  bf16* d = dst + (size_t)bh * 64 * 2048;
#pragma unroll
  for (int j = 0; j < 32; j += 8)
    tile[ty + j][tx] = s[(size_t)(t0 + ty + j) * 64 + d0 + tx];
  __syncthreads();
#pragma unroll
  for (int j = 0; j < 32; j += 8)
    d[(size_t)(d0 + ty + j) * 2048 + t0 + tx] = tile[tx][ty + j];
}

// ---------------------------------------------------------------------------
// m97-structure GEMM: C[M,N] = A[M,K] * BT[N,K]^T
// MODE 1: scatter Q,K,V row-major [BH][T][64]; MODE 2: fp32 store
// ---------------------------------------------------------------------------
template <int MODE>
__global__ __launch_bounds__(256) void gemm_kernel(
    const bf16* __restrict__ A, const bf16* __restrict__ BT,
    float* __restrict__ Cf, bf16* __restrict__ qb, bf16* __restrict__ kb,
    bf16* __restrict__ vb, int M, int N, int K) {
  __shared__ bf16 As[128 * 32];
  __shared__ bf16 Bs[128 * 32];
  const int t = threadIdx.x;
  const int w = t >> 6, l = t & 63;
  const int bm = blockIdx.y * 128, bn = blockIdx.x * 128;
  const int wr = (w >> 1) * 64, wc = (w & 1) * 64;
  const int lr = l & 15, lh = l >> 4;
  f32x4 acc[4][4] = {};

  const bf16* Ab = A + (size_t)bm * K;
  const bf16* Bb = BT + (size_t)bn * K;
  const int srow = t >> 2;
  const int scol = (t & 3) * 8;
  char* AsB = (char*)As;
  char* BsB = (char*)Bs;
  const int ldsw = w * 1024;

  for (int k0 = 0; k0 < K; k0 += 32) {
    __syncthreads();
    gld_lds16(Ab + (size_t)srow * K + k0 + scol, AsB + ldsw);
    gld_lds16(Ab + (size_t)(srow + 64) * K + k0 + scol, AsB + 4096 + ldsw);
    gld_lds16(Bb + (size_t)srow * K + k0 + scol, BsB + ldsw);
    gld_lds16(Bb + (size_t)(srow + 64) * K + k0 + scol, BsB + 4096 + ldsw);
    __syncthreads();
    bf16x8 af[4], bfr[4];
#pragma unroll
    for (int m = 0; m < 4; ++m)
      af[m] = *(const bf16x8*)(AsB + (wr + m * 16 + lr) * 64 + lh * 16);
#pragma unroll
    for (int n = 0; n < 4; ++n)
      bfr[n] = *(const bf16x8*)(BsB + (wc + n * 16 + lr) * 64 + lh * 16);
#pragma unroll
    for (int m = 0; m < 4; ++m)
#pragma unroll
      for (int n = 0; n < 4; ++n)
        acc[m][n] = __builtin_amdgcn_mfma_f32_16x16x32_bf16(af[m], bfr[n],
                                                            acc[m][n], 0, 0, 0);
  }

  const int r0 = bm + wr + (lh << 2);
  const int c0 = bn + wc + lr;
#pragma unroll
  for (int m = 0; m < 4; ++m) {
#pragma unroll
    for (int n = 0; n < 4; ++n) {
#pragma unroll
      for (int r = 0; r < 4; ++r) {
        float v = acc[m][n][r];
        int row = r0 + m * 16 + r;
        int col = c0 + n * 16;
        if (MODE == 2) {
          Cf[(size_t)row * N + col] = v;
        } else {
          int bb = row >> 11, tt = row & 2047;
          if (col < 1024) {
            int h = col >> 6, d = col & 63;
            qb[(((size_t)(bb * 16 + h)) * 2048 + tt) * 64 + d] = (bf16)v;
          } else if (col < 2048) {
            int c = col - 1024, h = c >> 6, d = c & 63;
            kb[(((size_t)(bb * 16 + h)) * 2048 + tt) * 64 + d] = (bf16)v;
          } else {
            int c = col - 2048, h = c >> 6, d = c & 63;
            vb[(((size_t)(bb * 16 + h)) * 2048 + tt) * 64 + d] = (bf16)v;
          }
        }
      }
    }
  }
}

// ---------------------------------------------------------------------------
// Causal flash attention, swapped-QK^T 32x32x16.
// 256 blocks x 512 thr = 8 waves. Wave w takes chunk jj=grp*4+(w&3) for w<4,
// 63-jj for w>=4: every chunk once; chunks c and 63-c land on the SAME SIMD
// (round-robin w%4) -> per-SIMD work constant (65 steps), 2 waves/SIMD for
// latency hiding (1 block/CU guaranteed: 160 VGPR * 16 waves > budget).
// Cross-lane via v_permlane32_swap (convention-independent). Prefetch is
// unconditional: final-step overrun (~4KB) lands in the next ws buffer.
// ---------------------------------------------------------------------------
__global__ __launch_bounds__(512, 2) void attn_kernel(const bf16* __restrict__ qb,
                                                      const bf16* __restrict__ kb,
                                                      const bf16* __restrict__ vt,
                                                      bf16* __restrict__ ao) {
  __shared__ bf16 plds[8][32][72];
  int wid = blockIdx.y * 8 + blockIdx.x;
  int swz = (wid & 7) * 32 + (wid >> 3);  // XCD x -> heads 4x..4x+3 (L2-resident)
  const int bh = swz >> 3;
  const int grp = swz & 7;
  const int w = threadIdx.x >> 6, l = threadIdx.x & 63;
  const int jj = grp * 4 + (w & 3);       // 0..31
  const int qc = (w >> 2) ? (63 - jj) : jj;  // chunk 0..63, each once
  const int qw = qc * 32;
  const int lastkt = qc;
  const int lq = l & 31, hi = l >> 5;
  const bf16* Qh = qb + (size_t)bh * 2048 * 64;
  const bf16* Kh = kb + (size_t)bh * 2048 * 64;
  const bf16* Vh = vt + (size_t)bh * 64 * 2048;
  const int bb = bh >> 4, h = bh & 15;
  const float sc2 = 0.125f * 1.4426950408889634f;  // scale * log2(e)

  // probe the swap's output convention once (wave-uniform result)
  unsigned ta = (unsigned)l, tb = (unsigned)l;
  plswap2(ta, tb);
  const bool flipped = (ta != (unsigned)(l & 31));

  bf16x8 qf[4];
#pragma unroll
  for (int c = 0; c < 4; ++c)
    qf[c] = *(const bf16x8*)(Qh + (size_t)(qw + lq) * 64 + c * 16 + hi * 8);

  f32x16 Ot0, Ot1;
#pragma unroll
  for (int r = 0; r < 16; ++r) { Ot0[r] = 0.f; Ot1[r] = 0.f; }
  float mrun = -1e30f, srun = 0.f;

  bf16x8 kA[4], vA[4], kB[4], vB[4];
#pragma unroll
  for (int c = 0; c < 4; ++c)
    kA[c] = *(const bf16x8*)(Kh + (size_t)lq * 64 + c * 16 + hi * 8);
#pragma unroll
  for (int df = 0; df < 2; ++df)
#pragma unroll
    for (int c = 0; c < 2; ++c)
      vA[df * 2 + c] = *(const bf16x8*)(Vh + (size_t)(df * 32 + lq) * 2048 + c * 16 + hi * 8);

  auto step = [&](bf16x8 (&KC)[4], bf16x8 (&VC)[4],
                  bf16x8 (&KN)[4], bf16x8 (&VN)[4], int kt) {
    const int nkv0 = (kt << 5) + 32;  // unconditional; OOB-safe (ws-internal)
#pragma unroll
    for (int c = 0; c < 4; ++c)
      KN[c] = *(const bf16x8*)(Kh + (size_t)(nkv0 + lq) * 64 + c * 16 + hi * 8);
#pragma unroll
    for (int df = 0; df < 2; ++df)
#pragma unroll
      for (int c = 0; c < 2; ++c)
        VN[df * 2 + c] = *(const bf16x8*)(Vh + (size_t)(df * 32 + lq) * 2048 + nkv0 + c * 16 + hi * 8);

    f32x16 S;
#pragma unroll
    for (int r = 0; r < 16; ++r) S[r] = 0.f;
#pragma unroll
    for (int c = 0; c < 4; ++c)
      S = __builtin_amdgcn_mfma_f32_32x32x16_bf16(KC[c], qf[c], S, 0, 0, 0);

    if (kt == lastkt) {  // causal diagonal tile (kv0 == qw)
#pragma unroll
      for (int r = 0; r < 16; ++r) {
        int kvl = (r & 3) + 8 * (r >> 2) + 4 * hi;
        if (kvl > lq) S[r] = -1e30f;
      }
    }

    float mx[8];
#pragma unroll
    for (int i = 0; i < 8; ++i) mx[i] = fmaxf(S[2 * i], S[2 * i + 1]);
#pragma unroll
    for (int i = 0; i < 4; ++i) mx[i] = fmaxf(mx[i], mx[i + 4]);
    mx[0] = fmaxf(mx[0], mx[2]); mx[1] = fmaxf(mx[1], mx[3]);
    float smax = fmaxf(mx[0], mx[1]);
    float vmax = plmax(smax);  // full-row max, convention-independent

    float mn = mrun;
    if (!__all(vmax <= mrun + 64.0f)) {  // 64 raw = 8 nat-exp units
      mn = fmaxf(mrun, vmax);
      float al = exp2f((mrun - mn) * sc2);
      srun *= al;
#pragma unroll
      for (int r = 0; r < 16; ++r) { Ot0[r] *= al; Ot1[r] *= al; }
      mrun = mn;
    }

    const float nb = -mn * sc2;
    float ps = 0.f;
    unsigned u_[8];
#pragma unroll
    for (int i = 0; i < 8; ++i) {
      float pa = exp2f(fmaf(S[2 * i], sc2, nb));
      float pb = exp2f(fmaf(S[2 * i + 1], sc2, nb));
      ps += pa + pb;
      u_[i] = pkbf(pa, pb);
    }
    srun += plsum(ps);  // full-row sum, convention-independent

    // P^T B-frags via permlane32_swap: one swap fills two output words.
    unsigned a0 = u_[0], b0 = u_[2]; plswap2(a0, b0);
    unsigned a1 = u_[1], b1 = u_[3]; plswap2(a1, b1);
    unsigned a2 = u_[4], b2 = u_[6]; plswap2(a2, b2);
    unsigned a3 = u_[5], b3 = u_[7]; plswap2(a3, b3);
    unsigned w00 = flipped ? b0 : a0, w02 = flipped ? a0 : b0;
    unsigned w01 = flipped ? b1 : a1, w03 = flipped ? a1 : b1;
    unsigned w10 = flipped ? b2 : a2, w12 = flipped ? a2 : b2;
    unsigned w11 = flipped ? b3 : a3, w13 = flipped ? a3 : b3;
    uint4v f0 = {w00, w01, w02, w03};
    uint4v f1 = {w10, w11, w12, w13};
    bf16x8 pf0 = __builtin_bit_cast(bf16x8, f0);
    bf16x8 pf1 = __builtin_bit_cast(bf16x8, f1);

    Ot0 = __builtin_amdgcn_mfma_f32_32x32x16_bf16(VC[0], pf0, Ot0, 0, 0, 0);
    Ot0 = __builtin_amdgcn_mfma_f32_32x32x16_bf16(VC[1], pf1, Ot0, 0, 0, 0);
    Ot1 = __builtin_amdgcn_mfma_f32_32x32x16_bf16(VC[2], pf0, Ot1, 0, 0, 0);
    Ot1 = __builtin_amdgcn_mfma_f32_32x32x16_bf16(VC[3], pf1, Ot1, 0, 0, 0);
  };

  for (int kt = 0; kt <= lastkt; ++kt) {
    if ((kt & 1) == 0) step(kA, vA, kB, vB, kt);
    else               step(kB, vB, kA, vA, kt);
  }

  // epilogue: O^T -> wave-private LDS transpose -> coalesced 16B stores
  float inv = 1.0f / srun;
#pragma unroll
  for (int r = 0; r < 16; r += 2) {
    int d0 = (r & 3) + 8 * (r >> 2) + 4 * hi;
    *(unsigned*)&plds[w][lq][d0]      = pkbf(Ot0[r] * inv, Ot0[r + 1] * inv);
    *(unsigned*)&plds[w][lq][32 + d0] = pkbf(Ot1[r] * inv, Ot1[r + 1] * inv);
  }
  __builtin_amdgcn_s_waitcnt(0);  // wave-private LDS RAW drain

  const int q = l >> 1, dh = (l & 1) * 32;
  size_t orow = ((size_t)(bb * 2048 + qw + q)) * 1024 + h * 64 + dh;
#pragma unroll
  for (int c = 0; c < 4; ++c) {
    bf16x8 vv = *(const bf16x8*)&plds[w][q][dh + c * 8];
    *(bf16x8*)(ao + orow + c * 8) = vv;
  }
}

// ---------------------------------------------------------------------------
// launch
// ---------------------------------------------------------------------------
extern "C" void kernel_launch(void* const* d_in, const int* in_sizes, int n_in,
                              void* d_out, int out_size, void* d_ws, size_t ws_size,
                              hipStream_t stream) {
  const float* x = (const float*)d_in[0];
  // d_in[1] = causal mask — implemented analytically
  const float* Wqkv = (const float*)d_in[2];
  const float* Wout = (const float*)d_in[3];
  float* out = (float*)d_out;

  char* ws = (char*)d_ws;
  bf16* xb  = (bf16*)(ws);                        // 8 MB
  bf16* wqT = (bf16*)(ws + (size_t)(8 << 20));    // 6 MB
  bf16* woT = (bf16*)(ws + (size_t)(14 << 20));   // 2 MB
  bf16* qb  = (bf16*)(ws + (size_t)(16 << 20));   // 8 MB
  bf16* kb  = (bf16*)(ws + (size_t)(24 << 20));   // 8 MB
  bf16* vt  = (bf16*)(ws + (size_t)(32 << 20));   // 8 MB  V^T
  bf16* ao  = (bf16*)(ws + (size_t)(40 << 20));   // 8 MB
  bf16* vb  = (bf16*)(ws + (size_t)(48 << 20));   // 8 MB  V row-major

  cvt_kernel<<<dim3(4096), dim3(256), 0, stream>>>(x, xb, 1048576);
  transpose_cvt_kernel<<<dim3(96, 32), dim3(256), 0, stream>>>(Wqkv, wqT, 1024, 3072);
  transpose_cvt_kernel<<<dim3(32, 32), dim3(256), 0, stream>>>(Wout, woT, 1024, 1024);
  gemm_kernel<1><<<dim3(24, 32), dim3(256), 0, stream>>>(xb, wqT, nullptr, qb, kb, vb,
                                                         4096, 3072, 1024);
  transpose_v_kernel<<<dim3(64, 2, 32), dim3(256), 0, stream>>>(vb, vt);
  attn_kernel<<<dim3(8, 32), dim3(512), 0, stream>>>(qb, kb, vt, ao);
  gemm_kernel<2><<<dim3(8, 32), dim3(256), 0, stream>>>(ao, woT, out, nullptr, nullptr,
                                                        nullptr, 4096, 1024, 1024);
}